// Round 3
// baseline (638.699 us; speedup 1.0000x reference)
//
#include <hip/hip_runtime.h>

#define N_NODES 100000
#define D_FEAT  128
#define N_EDGES 1600000
#define EPSBN   1e-5f
#define SLOPE   0.01f

typedef __attribute__((ext_vector_type(8))) short bf16x8;
typedef __attribute__((ext_vector_type(4))) float f32x4;
typedef unsigned short u16;
typedef unsigned int   u32;

__device__ __forceinline__ u16 f2bf(float f) {
    u32 x = __float_as_uint(f);
    u32 r = (x + 0x7fffu + ((x >> 16) & 1u)) >> 16;
    return (u16)r;
}

// ---------------- setup kernels ----------------

__global__ void k_init(int* deg_cnt, float* stats) {
    int i = blockIdx.x * 256 + threadIdx.x;
    if (i < N_NODES) deg_cnt[i] = 0;
    if (i < 1024) stats[i] = 0.f;
}

__global__ void k_deg(const int* __restrict__ dst, int* __restrict__ deg_cnt) {
    int e = blockIdx.x * 256 + threadIdx.x;
    if (e < N_EDGES) atomicAdd(&deg_cnt[dst[e]], 1);
}

__global__ void k_scanA(const int* __restrict__ cnt, int* __restrict__ bsums) {
    __shared__ int red[256];
    int i = blockIdx.x * 256 + threadIdx.x;
    red[threadIdx.x] = (i < N_NODES) ? cnt[i] : 0;
    __syncthreads();
    for (int s = 128; s > 0; s >>= 1) {
        if (threadIdx.x < s) red[threadIdx.x] += red[threadIdx.x + s];
        __syncthreads();
    }
    if (threadIdx.x == 0) bsums[blockIdx.x] = red[0];
}

__global__ void k_scanB(int* bsums, int nb) {  // exclusive scan in place, 1 block of 512
    __shared__ int sc[512];
    int t = threadIdx.x;
    sc[t] = (t < nb) ? bsums[t] : 0;
    __syncthreads();
    for (int off = 1; off < 512; off <<= 1) {
        int add = (t >= off) ? sc[t - off] : 0;
        __syncthreads();
        sc[t] += add;
        __syncthreads();
    }
    if (t < nb) bsums[t] = (t == 0) ? 0 : sc[t - 1];
}

__global__ void k_scanC(const int* __restrict__ cnt, const int* __restrict__ bsums_ex,
                        int* __restrict__ row_start, int* __restrict__ cursor,
                        float* __restrict__ dinv) {
    __shared__ int sc[256];
    int t = threadIdx.x;
    int i = blockIdx.x * 256 + t;
    int c = (i < N_NODES) ? cnt[i] : 0;
    sc[t] = c;
    __syncthreads();
    for (int off = 1; off < 256; off <<= 1) {
        int add = (t >= off) ? sc[t - off] : 0;
        __syncthreads();
        sc[t] += add;
        __syncthreads();
    }
    if (i < N_NODES) {
        int excl = sc[t] - c + bsums_ex[blockIdx.x];
        row_start[i] = excl;
        cursor[i]    = excl;
        dinv[i]      = rsqrtf((float)(c + 1));
    }
}

__global__ void k_csrfill(const int* __restrict__ src, const int* __restrict__ dst,
                          int* __restrict__ cursor, const float* __restrict__ dinv,
                          int* __restrict__ csr_src, float* __restrict__ csr_nrm) {
    int e = blockIdx.x * 256 + threadIdx.x;
    if (e >= N_EDGES) return;
    int s = src[e], d = dst[e];
    int slot = atomicAdd(&cursor[d], 1);
    csr_src[slot] = s;
    csr_nrm[slot] = dinv[s] * dinv[d];
}

// Pre-swizzle W (128x128 f32, row-major W[k][n]) into MFMA B-fragment order (bf16):
// frag t = (kc*8+nt)*64+lane holds 8 bf16: W[kc*32+(lane>>4)*8+j][nt*16+(lane&15)]
__global__ void k_swz(const float* __restrict__ W, u16* __restrict__ Wz) {
    int t = blockIdx.x * 256 + threadIdx.x;  // 0..2047
    int lane = t & 63, frag = t >> 6;
    int nt = frag & 7, kc = frag >> 3;
    int n  = nt * 16 + (lane & 15);
    int kb = kc * 32 + (lane >> 4) * 8;
    u16 tmp[8];
#pragma unroll
    for (int j = 0; j < 8; ++j) tmp[j] = f2bf(W[(kb + j) * 128 + n]);
#pragma unroll
    for (int j = 0; j < 8; ++j) Wz[t * 8 + j] = tmp[j];
}

// ---------------- GEMM: H[M x 128] = A[M x 128](f32, cvt->bf16) @ W(swizzled bf16) ----------------

__global__ __launch_bounds__(256) void k_gemm(const float* __restrict__ A,
                                              const u16* __restrict__ Wz,
                                              float* __restrict__ H, int M) {
    __shared__ u16 wl[16384];  // 32 KB
    int tid = threadIdx.x;
    {
        const uint4* s4 = (const uint4*)Wz;
        uint4* d4 = (uint4*)wl;
        for (int i = tid; i < 2048; i += 256) d4[i] = s4[i];
    }
    __syncthreads();
    int wave = tid >> 6, lane = tid & 63;
    long m0 = ((long)blockIdx.x * 4 + wave) * 16;
    if (m0 >= M) return;
    int mr = lane & 15, quad = lane >> 4;
    const float* arow = A + (size_t)(m0 + mr) * 128 + quad * 8;
    f32x4 acc[8] = {};
#pragma unroll
    for (int kc = 0; kc < 4; ++kc) {
        float4 a0 = *(const float4*)(arow + kc * 32);
        float4 a1 = *(const float4*)(arow + kc * 32 + 4);
        bf16x8 af;
        af[0] = (short)f2bf(a0.x); af[1] = (short)f2bf(a0.y);
        af[2] = (short)f2bf(a0.z); af[3] = (short)f2bf(a0.w);
        af[4] = (short)f2bf(a1.x); af[5] = (short)f2bf(a1.y);
        af[6] = (short)f2bf(a1.z); af[7] = (short)f2bf(a1.w);
        const u16* wb = wl + (kc * 4096 + lane * 8);   // fragment (kc,nt) at (kc*8+nt)*512
#pragma unroll
        for (int nt = 0; nt < 8; ++nt) {
            bf16x8 bf = *(const bf16x8*)(wb + nt * 512);
            acc[nt] = __builtin_amdgcn_mfma_f32_16x16x32_bf16(af, bf, acc[nt], 0, 0, 0);
        }
    }
    // C/D layout: col = lane&15, row = quad*4 + r
    float* hbase = H + m0 * 128 + (lane & 15);
#pragma unroll
    for (int nt = 0; nt < 8; ++nt)
#pragma unroll
        for (int r = 0; r < 4; ++r)
            hbase[(size_t)(quad * 4 + r) * 128 + nt * 16] = acc[nt][r];
}

// ---------------- aggregation: one wave per node, no atomics ----------------

__global__ __launch_bounds__(256) void k_agg(const float* __restrict__ H,
                                             const int* __restrict__ row_start,
                                             const int* __restrict__ cnt,
                                             const float* __restrict__ dinv,
                                             const int* __restrict__ csr_src,
                                             const float* __restrict__ csr_nrm,
                                             float* __restrict__ AGG) {
    int wave = threadIdx.x >> 6, lane = threadIdx.x & 63;
    int node = blockIdx.x * 4 + wave;  // grid exact: 25000*4 = 100000
    int start = row_start[node];
    int num   = cnt[node];
    float di  = dinv[node];
    float2 v = ((const float2*)(H + (size_t)node * 128))[lane];
    float ax = v.x * di * di, ay = v.y * di * di;  // self-loop
    for (int base = 0; base < num; base += 64) {
        int nb = num - base; if (nb > 64) nb = 64;
        int sidx = 0; float nrm0 = 0.f;
        if (lane < nb) {
            sidx = csr_src[start + base + lane];
            nrm0 = csr_nrm[start + base + lane];
        }
        for (int j = 0; j < nb; ++j) {
            int   s   = __shfl(sidx, j);
            float nrm = __shfl(nrm0, j);
            float2 hv = ((const float2*)(H + (size_t)s * 128))[lane];
            ax = fmaf(hv.x, nrm, ax);
            ay = fmaf(hv.y, nrm, ay);
        }
    }
    float2 o; o.x = ax; o.y = ay;
    ((float2*)(AGG + (size_t)node * 128))[lane] = o;
}

// ---------------- batch norm ----------------

__global__ void k_bnstats(const float* __restrict__ AGG, float* __restrict__ sums,
                          float* __restrict__ sumsq) {
    __shared__ float red[256];
    int col  = threadIdx.x & 127;
    int half = threadIdx.x >> 7;
    long r0 = (long)blockIdx.x * 400 + half;  // 250 blocks * 400 rows = 100000
    float s = 0.f, s2 = 0.f;
    for (int k = 0; k < 400; k += 2) {
        float v = AGG[(r0 + k) * 128 + col];
        s += v;
        s2 = fmaf(v, v, s2);
    }
    red[threadIdx.x] = s; __syncthreads();
    if (threadIdx.x < 128) atomicAdd(&sums[col], red[threadIdx.x] + red[threadIdx.x + 128]);
    __syncthreads();
    red[threadIdx.x] = s2; __syncthreads();
    if (threadIdx.x < 128) atomicAdd(&sumsq[col], red[threadIdx.x] + red[threadIdx.x + 128]);
}

__global__ void k_bnfin(const float* __restrict__ sums, const float* __restrict__ sumsq,
                        const float* __restrict__ g, const float* __restrict__ be,
                        float* __restrict__ scale, float* __restrict__ shift) {
    int c = threadIdx.x;  // 128 threads
    float mean = sums[c] * (1.f / N_NODES);
    float var  = sumsq[c] * (1.f / N_NODES) - mean * mean;
    float rstd = rsqrtf(var + EPSBN);
    float gg = g[c] * rstd;
    scale[c] = gg;
    shift[c] = be[c] - mean * gg;
}

// y = leaky(agg*scale + shift), f32 out (next-layer GEMM input)
__global__ void k_ew1(const float* __restrict__ AGG, const float* __restrict__ scale,
                      const float* __restrict__ shift, float* __restrict__ y) {
    long i = (long)blockIdx.x * 256 + threadIdx.x;  // one float2 per thread; 25000*256 = N*64
    int c2 = (int)(i & 63);
    float2 v  = ((const float2*)AGG)[i];
    float2 sc = ((const float2*)scale)[c2];
    float2 sh = ((const float2*)shift)[c2];
    float2 o;
    o.x = fmaf(v.x, sc.x, sh.x); o.x = o.x > 0.f ? o.x : o.x * SLOPE;
    o.y = fmaf(v.y, sc.y, sh.y); o.y = o.y > 0.f ? o.y : o.y * SLOPE;
    ((float2*)y)[i] = o;
}

// out = leaky(agg*scale + shift + x), f32 out
__global__ void k_ew2(const float* __restrict__ AGG, const float* __restrict__ scale,
                      const float* __restrict__ shift, const float* __restrict__ x,
                      float* __restrict__ out) {
    long i = (long)blockIdx.x * 256 + threadIdx.x;
    int c2 = (int)(i & 63);
    float2 v  = ((const float2*)AGG)[i];
    float2 sc = ((const float2*)scale)[c2];
    float2 sh = ((const float2*)shift)[c2];
    float2 xv = ((const float2*)x)[i];
    float2 o;
    o.x = fmaf(v.x, sc.x, sh.x) + xv.x; o.x = o.x > 0.f ? o.x : o.x * SLOPE;
    o.y = fmaf(v.y, sc.y, sh.y) + xv.y; o.y = o.y > 0.f ? o.y : o.y * SLOPE;
    ((float2*)out)[i] = o;
}

// ---------------- launch ----------------

extern "C" void kernel_launch(void* const* d_in, const int* in_sizes, int n_in,
                              void* d_out, int out_size, void* d_ws, size_t ws_size,
                              hipStream_t stream) {
    const float* x   = (const float*)d_in[0];
    const int*   ei  = (const int*)d_in[1];
    const float* W1  = (const float*)d_in[2];
    const float* g1  = (const float*)d_in[4];
    const float* be1 = (const float*)d_in[5];
    const float* W2  = (const float*)d_in[6];
    const float* g2  = (const float*)d_in[8];
    const float* be2 = (const float*)d_in[9];
    const int* src = ei;
    const int* dst = ei + N_EDGES;

    float* out = (float*)d_out;           // also used as 51.2 MB scratch before final write

    char* p = (char*)d_ws;
    float* bufA    = (float*)p; p += (size_t)N_NODES * 128 * 4;  // 51.2 MB
    int*   csr_src = (int*)p;   p += (size_t)N_EDGES * 4;        // 6.4 MB
    float* csr_nrm = (float*)p; p += (size_t)N_EDGES * 4;        // 6.4 MB
    int*   deg_cnt = (int*)p;   p += (size_t)N_NODES * 4;
    int*   row_st  = (int*)p;   p += (size_t)N_NODES * 4;
    int*   cursor  = (int*)p;   p += (size_t)N_NODES * 4;
    float* dinv    = (float*)p; p += (size_t)N_NODES * 4;
    int*   bsums   = (int*)p;   p += 512 * 4;
    float* stats   = (float*)p; p += 1024 * 4;
    u16*   wz1     = (u16*)p;   p += 16384 * 2;
    u16*   wz2     = (u16*)p;   p += 16384 * 2;

    float* sums1 = stats,       *sq1 = stats + 128, *scale1 = stats + 256, *shift1 = stats + 384;
    float* sums2 = stats + 512, *sq2 = stats + 640, *scale2 = stats + 768, *shift2 = stats + 896;

    // graph setup (shared by both layers)
    k_init<<<391, 256, 0, stream>>>(deg_cnt, stats);
    k_deg<<<6250, 256, 0, stream>>>(dst, deg_cnt);
    k_scanA<<<391, 256, 0, stream>>>(deg_cnt, bsums);
    k_scanB<<<1, 512, 0, stream>>>(bsums, 391);
    k_scanC<<<391, 256, 0, stream>>>(deg_cnt, bsums, row_st, cursor, dinv);
    k_csrfill<<<6250, 256, 0, stream>>>(src, dst, cursor, dinv, csr_src, csr_nrm);
    k_swz<<<8, 256, 0, stream>>>(W1, wz1);
    k_swz<<<8, 256, 0, stream>>>(W2, wz2);

    // layer 1:  H1 -> bufA,  AGG1 -> out(scratch),  Y1 -> bufA
    k_gemm<<<1563, 256, 0, stream>>>(x, wz1, bufA, N_NODES);
    k_agg<<<25000, 256, 0, stream>>>(bufA, row_st, deg_cnt, dinv, csr_src, csr_nrm, out);
    k_bnstats<<<250, 256, 0, stream>>>(out, sums1, sq1);
    k_bnfin<<<1, 128, 0, stream>>>(sums1, sq1, g1, be1, scale1, shift1);
    k_ew1<<<25000, 256, 0, stream>>>(out, scale1, shift1, bufA);

    // layer 2:  H2 -> out(scratch),  AGG2 -> bufA,  final -> out
    k_gemm<<<1563, 256, 0, stream>>>(bufA, wz2, out, N_NODES);
    k_agg<<<25000, 256, 0, stream>>>(out, row_st, deg_cnt, dinv, csr_src, csr_nrm, bufA);
    k_bnstats<<<250, 256, 0, stream>>>(bufA, sums2, sq2);
    k_bnfin<<<1, 128, 0, stream>>>(sums2, sq2, g2, be2, scale2, shift2);
    k_ew2<<<25000, 256, 0, stream>>>(bufA, scale2, shift2, x, out);
}

// Round 4
// 480.169 us; speedup vs baseline: 1.3302x; 1.3302x over previous
//
#include <hip/hip_runtime.h>

#define N_NODES 100000
#define D_FEAT  128
#define N_EDGES 1600000
#define EPSBN   1e-5f
#define SLOPE   0.01f

typedef __attribute__((ext_vector_type(8))) short bf16x8;
typedef __attribute__((ext_vector_type(4))) float f32x4;
typedef unsigned short u16;
typedef unsigned int   u32;

__device__ __forceinline__ u16 f2bf(float f) {
    u32 x = __float_as_uint(f);
    u32 r = (x + 0x7fffu + ((x >> 16) & 1u)) >> 16;
    return (u16)r;
}
__device__ __forceinline__ float bf_lo(u32 w) { return __uint_as_float(w << 16); }
__device__ __forceinline__ float bf_hi(u32 w) { return __uint_as_float(w & 0xffff0000u); }

// ---------------- setup kernels ----------------

__global__ void k_init(int* deg_cnt, float* stats) {
    int i = blockIdx.x * 256 + threadIdx.x;
    if (i < N_NODES) deg_cnt[i] = 0;
    if (i < 1024) stats[i] = 0.f;
}

__global__ void k_deg(const int* __restrict__ dst, int* __restrict__ deg_cnt) {
    int e = blockIdx.x * 256 + threadIdx.x;
    if (e < N_EDGES) atomicAdd(&deg_cnt[dst[e]], 1);
}

__global__ void k_scanA(const int* __restrict__ cnt, int* __restrict__ bsums) {
    __shared__ int red[256];
    int i = blockIdx.x * 256 + threadIdx.x;
    red[threadIdx.x] = (i < N_NODES) ? cnt[i] : 0;
    __syncthreads();
    for (int s = 128; s > 0; s >>= 1) {
        if (threadIdx.x < s) red[threadIdx.x] += red[threadIdx.x + s];
        __syncthreads();
    }
    if (threadIdx.x == 0) bsums[blockIdx.x] = red[0];
}

__global__ void k_scanB(int* bsums, int nb) {  // exclusive scan in place
    __shared__ int sc[512];
    int t = threadIdx.x;
    sc[t] = (t < nb) ? bsums[t] : 0;
    __syncthreads();
    for (int off = 1; off < 512; off <<= 1) {
        int add = (t >= off) ? sc[t - off] : 0;
        __syncthreads();
        sc[t] += add;
        __syncthreads();
    }
    if (t < nb) bsums[t] = (t == 0) ? 0 : sc[t - 1];
}

__global__ void k_scanC(const int* __restrict__ cnt, const int* __restrict__ bsums_ex,
                        int* __restrict__ row_start, int* __restrict__ cursor,
                        float* __restrict__ dinv) {
    __shared__ int sc[256];
    int t = threadIdx.x;
    int i = blockIdx.x * 256 + t;
    int c = (i < N_NODES) ? cnt[i] : 0;
    sc[t] = c;
    __syncthreads();
    for (int off = 1; off < 256; off <<= 1) {
        int add = (t >= off) ? sc[t - off] : 0;
        __syncthreads();
        sc[t] += add;
        __syncthreads();
    }
    if (i < N_NODES) {
        int excl = sc[t] - c + bsums_ex[blockIdx.x];
        row_start[i] = excl;
        cursor[i]    = excl;
        dinv[i]      = rsqrtf((float)(c + 1));
    }
}

__global__ void k_csrfill(const int* __restrict__ src, const int* __restrict__ dst,
                          int* __restrict__ cursor, const float* __restrict__ dinv,
                          int2* __restrict__ csr) {
    int e = blockIdx.x * 256 + threadIdx.x;
    if (e >= N_EDGES) return;
    int s = src[e], d = dst[e];
    int slot = atomicAdd(&cursor[d], 1);
    int2 pk; pk.x = s; pk.y = __float_as_int(dinv[s] * dinv[d]);
    csr[slot] = pk;
}

// Pre-swizzle W (128x128 f32, row-major W[k][n]) into MFMA B-fragment order (bf16):
// frag t = (kc*8+nt)*64+lane holds 8 bf16: W[kc*32+(lane>>4)*8+j][nt*16+(lane&15)]
__global__ void k_swz(const float* __restrict__ W, u16* __restrict__ Wz) {
    int t = blockIdx.x * 256 + threadIdx.x;  // 0..2047
    int lane = t & 63, frag = t >> 6;
    int nt = frag & 7, kc = frag >> 3;
    int n  = nt * 16 + (lane & 15);
    int kb = kc * 32 + (lane >> 4) * 8;
    u16 tmp[8];
#pragma unroll
    for (int j = 0; j < 8; ++j) tmp[j] = f2bf(W[(kb + j) * 128 + n]);
#pragma unroll
    for (int j = 0; j < 8; ++j) Wz[t * 8 + j] = tmp[j];
}

// ---- GEMM: Hb[M x 128](bf16) = act(A[M x 128] f32) @ W ; FUSE: act = leaky(A*scale+shift)

template <bool FUSE>
__global__ __launch_bounds__(256) void k_gemm(const float* __restrict__ A,
                                              const u16* __restrict__ Wz,
                                              const float* __restrict__ scale,
                                              const float* __restrict__ shift,
                                              u16* __restrict__ Hb, int M) {
    __shared__ u16 wl[16384];  // 32 KB
    __shared__ float sLds[128], hLds[128];
    int tid = threadIdx.x;
    {
        const uint4* s4 = (const uint4*)Wz;
        uint4* d4 = (uint4*)wl;
        for (int i = tid; i < 2048; i += 256) d4[i] = s4[i];
    }
    if (FUSE && tid < 128) { sLds[tid] = scale[tid]; hLds[tid] = shift[tid]; }
    __syncthreads();
    int wave = tid >> 6, lane = tid & 63;
    long m0 = ((long)blockIdx.x * 4 + wave) * 16;
    if (m0 >= M) return;
    int mr = lane & 15, quad = lane >> 4;
    const float* arow = A + (size_t)(m0 + mr) * 128 + quad * 8;
    f32x4 acc[8] = {};
#pragma unroll
    for (int kc = 0; kc < 4; ++kc) {
        float4 a0 = *(const float4*)(arow + kc * 32);
        float4 a1 = *(const float4*)(arow + kc * 32 + 4);
        float av[8] = {a0.x, a0.y, a0.z, a0.w, a1.x, a1.y, a1.z, a1.w};
        if (FUSE) {
            int c = kc * 32 + quad * 8;
#pragma unroll
            for (int j = 0; j < 8; ++j) {
                float v = fmaf(av[j], sLds[c + j], hLds[c + j]);
                av[j] = v > 0.f ? v : v * SLOPE;
            }
        }
        bf16x8 af;
#pragma unroll
        for (int j = 0; j < 8; ++j) af[j] = (short)f2bf(av[j]);
        const u16* wb = wl + (kc * 4096 + lane * 8);  // fragment (kc,nt) at (kc*8+nt)*512
#pragma unroll
        for (int nt = 0; nt < 8; ++nt) {
            bf16x8 bf = *(const bf16x8*)(wb + nt * 512);
            acc[nt] = __builtin_amdgcn_mfma_f32_16x16x32_bf16(af, bf, acc[nt], 0, 0, 0);
        }
    }
    // C/D layout: col = lane&15, row = quad*4 + r  -> store bf16
    u16* hb = Hb + (size_t)m0 * 128 + (lane & 15);
#pragma unroll
    for (int nt = 0; nt < 8; ++nt)
#pragma unroll
        for (int r = 0; r < 4; ++r)
            hb[(size_t)(quad * 4 + r) * 128 + nt * 16] = f2bf(acc[nt][r]);
}

// ---------------- aggregation: one wave per node, bf16 gathers, no atomics ----------------

__global__ __launch_bounds__(256) void k_agg(const u32* __restrict__ Hb,  // 64 u32 per row
                                             const int* __restrict__ row_start,
                                             const int* __restrict__ cnt,
                                             const float* __restrict__ dinv,
                                             const int2* __restrict__ csr,
                                             float* __restrict__ AGG) {
    int wave = threadIdx.x >> 6, lane = threadIdx.x & 63;
    int node = blockIdx.x * 4 + wave;  // 25000*4 = 100000 exact
    int start = row_start[node];
    int num   = cnt[node];
    float di  = dinv[node];
    u32 selfw = Hb[(size_t)node * 64 + lane];
    float ax = bf_lo(selfw) * di * di, ay = bf_hi(selfw) * di * di;  // self-loop
    for (int base = 0; base < num; base += 64) {
        int nb = num - base; if (nb > 64) nb = 64;
        int2 pk; pk.x = 0; pk.y = 0;
        if (lane < nb) pk = csr[start + base + lane];
        int j = 0;
        for (; j + 3 < nb; j += 4) {
            int   s0 = __shfl(pk.x, j),     s1 = __shfl(pk.x, j + 1);
            int   s2 = __shfl(pk.x, j + 2), s3 = __shfl(pk.x, j + 3);
            float n0 = __int_as_float(__shfl(pk.y, j));
            float n1 = __int_as_float(__shfl(pk.y, j + 1));
            float n2 = __int_as_float(__shfl(pk.y, j + 2));
            float n3 = __int_as_float(__shfl(pk.y, j + 3));
            u32 w0 = Hb[(size_t)s0 * 64 + lane];
            u32 w1 = Hb[(size_t)s1 * 64 + lane];
            u32 w2 = Hb[(size_t)s2 * 64 + lane];
            u32 w3 = Hb[(size_t)s3 * 64 + lane];
            ax = fmaf(bf_lo(w0), n0, ax); ay = fmaf(bf_hi(w0), n0, ay);
            ax = fmaf(bf_lo(w1), n1, ax); ay = fmaf(bf_hi(w1), n1, ay);
            ax = fmaf(bf_lo(w2), n2, ax); ay = fmaf(bf_hi(w2), n2, ay);
            ax = fmaf(bf_lo(w3), n3, ax); ay = fmaf(bf_hi(w3), n3, ay);
        }
        for (; j < nb; ++j) {
            int   s = __shfl(pk.x, j);
            float n = __int_as_float(__shfl(pk.y, j));
            u32 w = Hb[(size_t)s * 64 + lane];
            ax = fmaf(bf_lo(w), n, ax); ay = fmaf(bf_hi(w), n, ay);
        }
    }
    float2 o; o.x = ax; o.y = ay;
    ((float2*)(AGG + (size_t)node * 128))[lane] = o;
}

// ---------------- batch norm ----------------

__global__ void k_bnstats(const float* __restrict__ AGG, float* __restrict__ sums,
                          float* __restrict__ sumsq) {
    __shared__ float red[256];
    int col  = threadIdx.x & 127;
    int half = threadIdx.x >> 7;
    long r0 = (long)blockIdx.x * 400 + half;  // 250 blocks * 400 rows = 100000
    float s = 0.f, s2 = 0.f;
    for (int k = 0; k < 400; k += 2) {
        float v = AGG[(r0 + k) * 128 + col];
        s += v;
        s2 = fmaf(v, v, s2);
    }
    red[threadIdx.x] = s; __syncthreads();
    if (threadIdx.x < 128) atomicAdd(&sums[col], red[threadIdx.x] + red[threadIdx.x + 128]);
    __syncthreads();
    red[threadIdx.x] = s2; __syncthreads();
    if (threadIdx.x < 128) atomicAdd(&sumsq[col], red[threadIdx.x] + red[threadIdx.x + 128]);
}

__global__ void k_bnfin(const float* __restrict__ sums, const float* __restrict__ sumsq,
                        const float* __restrict__ g, const float* __restrict__ be,
                        float* __restrict__ scale, float* __restrict__ shift) {
    int c = threadIdx.x;  // 128 threads
    float mean = sums[c] * (1.f / N_NODES);
    float var  = sumsq[c] * (1.f / N_NODES) - mean * mean;
    float rstd = rsqrtf(var + EPSBN);
    float gg = g[c] * rstd;
    scale[c] = gg;
    shift[c] = be[c] - mean * gg;
}

// out = leaky(agg*scale + shift + x), f32 out
__global__ void k_ew2(const float* __restrict__ AGG, const float* __restrict__ scale,
                      const float* __restrict__ shift, const float* __restrict__ x,
                      float* __restrict__ out) {
    long i = (long)blockIdx.x * 256 + threadIdx.x;
    int c2 = (int)(i & 63);
    float2 v  = ((const float2*)AGG)[i];
    float2 sc = ((const float2*)scale)[c2];
    float2 sh = ((const float2*)shift)[c2];
    float2 xv = ((const float2*)x)[i];
    float2 o;
    o.x = fmaf(v.x, sc.x, sh.x) + xv.x; o.x = o.x > 0.f ? o.x : o.x * SLOPE;
    o.y = fmaf(v.y, sc.y, sh.y) + xv.y; o.y = o.y > 0.f ? o.y : o.y * SLOPE;
    ((float2*)out)[i] = o;
}

// ---------------- launch ----------------

extern "C" void kernel_launch(void* const* d_in, const int* in_sizes, int n_in,
                              void* d_out, int out_size, void* d_ws, size_t ws_size,
                              hipStream_t stream) {
    const float* x   = (const float*)d_in[0];
    const int*   ei  = (const int*)d_in[1];
    const float* W1  = (const float*)d_in[2];
    const float* g1  = (const float*)d_in[4];
    const float* be1 = (const float*)d_in[5];
    const float* W2  = (const float*)d_in[6];
    const float* g2  = (const float*)d_in[8];
    const float* be2 = (const float*)d_in[9];
    const int* src = ei;
    const int* dst = ei + N_EDGES;

    float* out = (float*)d_out;
    u16*   Hb  = (u16*)d_out;  // 25.6 MB bf16 H lives in d_out until ew2 overwrites it

    char* p = (char*)d_ws;
    float* bufA    = (float*)p; p += (size_t)N_NODES * 128 * 4;  // 51.2 MB (AGG1 then AGG2)
    int2*  csr     = (int2*)p;  p += (size_t)N_EDGES * 8;        // 12.8 MB
    int*   deg_cnt = (int*)p;   p += (size_t)N_NODES * 4;
    int*   row_st  = (int*)p;   p += (size_t)N_NODES * 4;
    int*   cursor  = (int*)p;   p += (size_t)N_NODES * 4;
    float* dinv    = (float*)p; p += (size_t)N_NODES * 4;
    int*   bsums   = (int*)p;   p += 512 * 4;
    float* stats   = (float*)p; p += 1024 * 4;
    u16*   wz1     = (u16*)p;   p += 16384 * 2;
    u16*   wz2     = (u16*)p;   p += 16384 * 2;

    float* sums1 = stats,       *sq1 = stats + 128, *scale1 = stats + 256, *shift1 = stats + 384;
    float* sums2 = stats + 512, *sq2 = stats + 640, *scale2 = stats + 768, *shift2 = stats + 896;

    // graph setup (shared by both layers)
    k_init<<<391, 256, 0, stream>>>(deg_cnt, stats);
    k_deg<<<6250, 256, 0, stream>>>(dst, deg_cnt);
    k_scanA<<<391, 256, 0, stream>>>(deg_cnt, bsums);
    k_scanB<<<1, 512, 0, stream>>>(bsums, 391);
    k_scanC<<<391, 256, 0, stream>>>(deg_cnt, bsums, row_st, cursor, dinv);
    k_csrfill<<<6250, 256, 0, stream>>>(src, dst, cursor, dinv, csr);
    k_swz<<<8, 256, 0, stream>>>(W1, wz1);
    k_swz<<<8, 256, 0, stream>>>(W2, wz2);

    // layer 1:  Hb1 -> d_out (bf16),  AGG1 -> bufA
    k_gemm<false><<<1563, 256, 0, stream>>>(x, wz1, nullptr, nullptr, Hb, N_NODES);
    k_agg<<<25000, 256, 0, stream>>>((const u32*)Hb, row_st, deg_cnt, dinv, csr, bufA);
    k_bnstats<<<250, 256, 0, stream>>>(bufA, sums1, sq1);
    k_bnfin<<<1, 128, 0, stream>>>(sums1, sq1, g1, be1, scale1, shift1);

    // layer 2:  A = leaky(BN1(AGG1)) fused;  Hb2 -> d_out (bf16);  AGG2 -> bufA
    k_gemm<true><<<1563, 256, 0, stream>>>(bufA, wz2, scale1, shift1, Hb, N_NODES);
    k_agg<<<25000, 256, 0, stream>>>((const u32*)Hb, row_st, deg_cnt, dinv, csr, bufA);
    k_bnstats<<<250, 256, 0, stream>>>(bufA, sums2, sq2);
    k_bnfin<<<1, 128, 0, stream>>>(sums2, sq2, g2, be2, scale2, shift2);
    k_ew2<<<25000, 256, 0, stream>>>(bufA, scale2, shift2, x, out);
}